// Round 1
// baseline (748.569 us; speedup 1.0000x reference)
//
#include <hip/hip_runtime.h>
#include <stdint.h>

#define NEGF  (-3.402823466e38f)
#define TOPK  64

typedef __attribute__((ext_vector_type(8))) short bfrag8;
typedef __attribute__((ext_vector_type(4))) float f32x4;

static __device__ __forceinline__ unsigned short f2bf(float f) {
  union { float f; unsigned u; } c; c.f = f;
  unsigned u = c.u;
  return (unsigned short)((u + 0x7fffu + ((u >> 16) & 1u)) >> 16);
}
static __device__ __forceinline__ unsigned mono(float x) {
  union { float f; unsigned u; } c; c.f = x;
  return (c.u & 0x80000000u) ? ~c.u : (c.u | 0x80000000u);
}
static __device__ __forceinline__ float invmono(unsigned k) {
  union { unsigned u; float f; } c;
  c.u = (k & 0x80000000u) ? (k ^ 0x80000000u) : ~k;
  return c.f;
}
static __device__ __forceinline__ int waveSum(int v) {
  #pragma unroll
  for (int o = 1; o < 64; o <<= 1) v += __shfl_xor(v, o);
  return v;
}
static __device__ __forceinline__ float waveSumF(float v) {
  #pragma unroll
  for (int o = 1; o < 64; o <<= 1) v += __shfl_xor(v, o);
  return v;
}
static __device__ __forceinline__ unsigned waveMaxU(unsigned v) {
  #pragma unroll
  for (int o = 1; o < 64; o <<= 1) {
    unsigned t = (unsigned)__shfl_xor((int)v, o);
    v = v > t ? v : t;
  }
  return v;
}

// ---------------- transpose: in f32 [R][C] -> out (f32 or bf16) [C][R] ----------------
template<int OBF>
__global__ __launch_bounds__(256) void transpose_k(const float* __restrict__ in,
                                                   void* __restrict__ out, int R, int C) {
  __shared__ float t[32][33];
  int c0 = blockIdx.x * 32, r0 = blockIdx.y * 32;
  int tx = threadIdx.x & 31, ty = (threadIdx.x >> 5) * 4;
  #pragma unroll
  for (int i = 0; i < 4; i++)
    t[ty + i][tx] = in[(size_t)(r0 + ty + i) * C + c0 + tx];
  __syncthreads();
  #pragma unroll
  for (int i = 0; i < 4; i++) {
    float v = t[tx][ty + i];
    size_t idx = (size_t)(c0 + ty + i) * R + r0 + tx;
    if (OBF) ((unsigned short*)out)[idx] = f2bf(v);
    else     ((float*)out)[idx] = v;
  }
}

// ---------------- fp32 GEMM: C = A[M,K] x Bt[N,K]^T ----------------
// MODE 0: projection epilogue: m->(b=m>>11,l), n->(h=n>>6,dd); out[((b*8+h)*2048+l)*64+dd]=acc*scale
// MODE 1: logits epilogue: per-z slice, out[m*N+n] = acc
template<int MODE>
__global__ __launch_bounds__(256) void gemm_f32_abt(const float* __restrict__ A,
    const float* __restrict__ Bt, float* __restrict__ C,
    int M, int N, int K, float scale) {
  __shared__ float As[64][65];   // [m][k], stride 65 (bank-spread, scalar access)
  __shared__ float Bs[64][65];   // [n][k]
  int tid = threadIdx.x;
  int tx = tid & 15, ty = tid >> 4;
  int m0 = blockIdx.y * 64, n0 = blockIdx.x * 64;
  const float* Ap = A; const float* Bp = Bt; float* Cp = C;
  if (MODE == 1) {
    size_t z = blockIdx.z;
    Ap += z * (size_t)M * K;
    Bp += z * (size_t)N * K;
    Cp += z * (size_t)M * N;
  }
  float acc[4][4] = {};
  for (int k0 = 0; k0 < K; k0 += 64) {
    #pragma unroll
    for (int i = 0; i < 4; i++) {
      int f = tid + (i << 8);
      int row = f >> 4, kc = (f & 15) << 2;
      float4 av = *(const float4*)(Ap + (size_t)(m0 + row) * K + k0 + kc);
      As[row][kc+0] = av.x; As[row][kc+1] = av.y; As[row][kc+2] = av.z; As[row][kc+3] = av.w;
      float4 bv = *(const float4*)(Bp + (size_t)(n0 + row) * K + k0 + kc);
      Bs[row][kc+0] = bv.x; Bs[row][kc+1] = bv.y; Bs[row][kc+2] = bv.z; Bs[row][kc+3] = bv.w;
    }
    __syncthreads();
    #pragma unroll 4
    for (int d = 0; d < 64; d++) {
      float a[4], b[4];
      #pragma unroll
      for (int i = 0; i < 4; i++) a[i] = As[ty*4 + i][d];
      #pragma unroll
      for (int j = 0; j < 4; j++) b[j] = Bs[tx*4 + j][d];
      #pragma unroll
      for (int i = 0; i < 4; i++)
        #pragma unroll
        for (int j = 0; j < 4; j++)
          acc[i][j] = fmaf(a[i], b[j], acc[i][j]);
    }
    __syncthreads();
  }
  #pragma unroll
  for (int i = 0; i < 4; i++) {
    int m = m0 + ty*4 + i;
    float4 v4;
    v4.x = acc[i][0]*scale; v4.y = acc[i][1]*scale; v4.z = acc[i][2]*scale; v4.w = acc[i][3]*scale;
    if (MODE == 0) {
      int b = m >> 11, l = m & 2047;
      int n = n0 + tx*4;
      int h = n >> 6, dd = n & 63;
      *(float4*)(Cp + ((((size_t)b*8 + h)*2048 + l)*64 + dd)) = v4;
    } else {
      *(float4*)(Cp + (size_t)m * N + n0 + tx*4) = v4;
    }
  }
}

// ---------------- bf16 MFMA GEMM: C = A[M,K] x Bt[N,K]^T ----------------
// BM=64, BN=128, BK=64, 4 waves (2x2), per-wave 32x64 via 2x4 of 16x16x32 MFMA.
// MODE 0 (v_proj): m->(b,l), n->(h=n>>9,d); out bf16 vpT[((b*8+h)*512+d)*2048+l]
// MODE 1 (PV):     z=(b*8+h); out bf16 mixed[(b*2048+l)*4096 + h*512 + n]
// MODE 2 (fc):     out f32 [m*512+n]
template<typename AT, int MODE>
__global__ __launch_bounds__(256) void gemm_bf16(const AT* __restrict__ A,
    const unsigned short* __restrict__ Bt, void* __restrict__ Cout,
    int M, int N, int K) {
  __shared__ unsigned short As[64][72];
  __shared__ unsigned short Bs[128][72];
  int tid = threadIdx.x;
  int lane = tid & 63, wave = tid >> 6;
  int wr = wave >> 1, wc = wave & 1;
  int m0 = blockIdx.y * 64, n0 = blockIdx.x * 128;
  int z = blockIdx.z;
  const AT* Ap = A; const unsigned short* Bp = Bt;
  if (MODE == 1) { Ap += (size_t)z * M * K; Bp += (size_t)z * N * K; }
  f32x4 acc[2][4];
  #pragma unroll
  for (int mi = 0; mi < 2; mi++)
    #pragma unroll
    for (int ni = 0; ni < 4; ni++) acc[mi][ni] = (f32x4){0.f, 0.f, 0.f, 0.f};
  int arow = tid >> 2, akc = (tid & 3) << 4;
  int brow = tid >> 1, bkc = (tid & 1) << 5;
  for (int k0 = 0; k0 < K; k0 += 64) {
    { // stage A (64x64), convert f32->bf16 if needed
      const AT* src = Ap + (size_t)(m0 + arow) * K + k0 + akc;
      if constexpr (sizeof(AT) == 4) {
        const float* s = (const float*)src;
        float4 x0 = *(const float4*)(s + 0);
        float4 x1 = *(const float4*)(s + 4);
        float4 x2 = *(const float4*)(s + 8);
        float4 x3 = *(const float4*)(s + 12);
        union { bfrag8 v; unsigned short u[8]; } p0, p1;
        p0.u[0]=f2bf(x0.x); p0.u[1]=f2bf(x0.y); p0.u[2]=f2bf(x0.z); p0.u[3]=f2bf(x0.w);
        p0.u[4]=f2bf(x1.x); p0.u[5]=f2bf(x1.y); p0.u[6]=f2bf(x1.z); p0.u[7]=f2bf(x1.w);
        p1.u[0]=f2bf(x2.x); p1.u[1]=f2bf(x2.y); p1.u[2]=f2bf(x2.z); p1.u[3]=f2bf(x2.w);
        p1.u[4]=f2bf(x3.x); p1.u[5]=f2bf(x3.y); p1.u[6]=f2bf(x3.z); p1.u[7]=f2bf(x3.w);
        *(bfrag8*)&As[arow][akc + 0] = p0.v;
        *(bfrag8*)&As[arow][akc + 8] = p1.v;
      } else {
        const bfrag8* s = (const bfrag8*)src;
        *(bfrag8*)&As[arow][akc + 0] = s[0];
        *(bfrag8*)&As[arow][akc + 8] = s[1];
      }
    }
    { // stage B (128x64), always bf16 source
      const bfrag8* s = (const bfrag8*)(Bp + (size_t)(n0 + brow) * K + k0 + bkc);
      #pragma unroll
      for (int j = 0; j < 4; j++)
        *(bfrag8*)&Bs[brow][bkc + 8*j] = s[j];
    }
    __syncthreads();
    #pragma unroll
    for (int kh = 0; kh < 2; kh++) {
      int krd = (kh << 5) + ((lane >> 4) << 3);
      bfrag8 af[2], bfr[4];
      #pragma unroll
      for (int mi = 0; mi < 2; mi++)
        af[mi] = *(const bfrag8*)&As[wr*32 + mi*16 + (lane & 15)][krd];
      #pragma unroll
      for (int ni = 0; ni < 4; ni++)
        bfr[ni] = *(const bfrag8*)&Bs[wc*64 + ni*16 + (lane & 15)][krd];
      #pragma unroll
      for (int mi = 0; mi < 2; mi++)
        #pragma unroll
        for (int ni = 0; ni < 4; ni++)
          acc[mi][ni] = __builtin_amdgcn_mfma_f32_16x16x32_bf16(af[mi], bfr[ni], acc[mi][ni], 0, 0, 0);
    }
    __syncthreads();
  }
  #pragma unroll
  for (int mi = 0; mi < 2; mi++) {
    int rb = m0 + wr*32 + mi*16 + ((lane >> 4) << 2);
    #pragma unroll
    for (int ni = 0; ni < 4; ni++) {
      int col = n0 + wc*64 + ni*16 + (lane & 15);
      f32x4 v = acc[mi][ni];
      if (MODE == 0) {
        int b = rb >> 11, l = rb & 2047;
        int h = col >> 9, d = col & 511;
        unsigned short* o = (unsigned short*)Cout + ((((size_t)b*8 + h)*512 + d)*2048 + l);
        ushort4 u;
        u.x = f2bf(v[0]); u.y = f2bf(v[1]); u.z = f2bf(v[2]); u.w = f2bf(v[3]);
        *(ushort4*)o = u;
      } else if (MODE == 1) {
        int b = z >> 3, h = z & 7;
        unsigned short* o = (unsigned short*)Cout;
        #pragma unroll
        for (int j = 0; j < 4; j++)
          o[((size_t)b*2048 + rb + j)*4096 + h*512 + col] = f2bf(v[j]);
      } else {
        float* o = (float*)Cout;
        #pragma unroll
        for (int j = 0; j < 4; j++)
          o[(size_t)(rb + j)*512 + col] = v[j];
      }
    }
  }
}

// ---------------- per-row top-k + softmax (one wave per row, in-place) ----------------
__global__ __launch_bounds__(256) void topk_softmax_k(float* __restrict__ probs,
    const int* __restrict__ mask, const float* __restrict__ qmaskf) {
  int lane = threadIdx.x & 63;
  int row = blockIdx.x * 4 + (threadIdx.x >> 6);   // (b*8+h)*2048 + q
  int b = row >> 14, q = row & 2047;
  float* rp = probs + (size_t)row * 2048;
  const int* mp = mask + ((size_t)b * 2048 + q) * 2048;
  unsigned key[32];
  #pragma unroll
  for (int j = 0; j < 8; j++) {
    int base = (lane << 2) + (j << 8);
    float4 v = *(const float4*)(rp + base);
    int4 mm = *(const int4*)(mp + base);
    key[4*j+0] = mono(mm.x == 0 ? NEGF : v.x);
    key[4*j+1] = mono(mm.y == 0 ? NEGF : v.y);
    key[4*j+2] = mono(mm.z == 0 ? NEGF : v.z);
    key[4*j+3] = mono(mm.w == 0 ? NEGF : v.w);
  }
  unsigned drop = 0;
  bool qm = qmaskf[b * 2048 + q] > 0.5f;
  if (qm) {
    // exact 64th-largest key via binary search on u32 key space
    unsigned lo = 0u, hi = 0xFFFFFFFFu;
    while (lo < hi) {
      unsigned mid = lo + ((hi - lo) >> 1) + 1u;
      int c = 0;
      #pragma unroll
      for (int e = 0; e < 32; e++) c += (key[e] >= mid) ? 1 : 0;
      c = waveSum(c);
      if (c >= TOPK) lo = mid; else hi = mid - 1u;
    }
    unsigned K64 = lo;
    int cgt = 0, ceq = 0;
    #pragma unroll
    for (int e = 0; e < 32; e++) { cgt += (key[e] > K64) ? 1 : 0; ceq += (key[e] == K64) ? 1 : 0; }
    cgt = waveSum(cgt);
    int ceqT = waveSum(ceq);
    int r = TOPK - cgt;
    #pragma unroll
    for (int e = 0; e < 32; e++) if (key[e] < K64) drop |= (1u << e);
    if (ceqT > r) {
      // rare tie at the boundary: keep lowest-index equals (matches lax.top_k)
      int taken = 0;
      for (int j = 0; j < 8; j++) {
        int cl = 0, eqm = 0;
        #pragma unroll
        for (int t = 0; t < 4; t++)
          if (key[4*j+t] == K64) { eqm |= (1 << t); cl++; }
        int incl = cl;
        for (int o = 1; o < 64; o <<= 1) {
          int tt = __shfl_up(incl, o);
          if (lane >= o) incl += tt;
        }
        int pref = incl - cl;
        int tot = __shfl(incl, 63);
        int rk = taken + pref;
        #pragma unroll
        for (int t = 0; t < 4; t++) {
          if ((eqm >> t) & 1) {
            if (rk >= r) drop |= (1u << (4*j+t));
            rk++;
          }
        }
        taken += tot;
      }
    }
  }
  unsigned kmax = 0;
  #pragma unroll
  for (int e = 0; e < 32; e++)
    if (!((drop >> e) & 1u)) kmax = kmax > key[e] ? kmax : key[e];
  kmax = waveMaxU(kmax);
  float mx = invmono(kmax);
  float ex[32]; float s = 0.f;
  #pragma unroll
  for (int e = 0; e < 32; e++) {
    float t = ((drop >> e) & 1u) ? 0.f : expf(invmono(key[e]) - mx);
    ex[e] = t; s += t;
  }
  s = waveSumF(s);
  float inv = 1.0f / s;
  #pragma unroll
  for (int j = 0; j < 8; j++) {
    int base = (lane << 2) + (j << 8);
    float4 o;
    o.x = ex[4*j+0]*inv; o.y = ex[4*j+1]*inv; o.z = ex[4*j+2]*inv; o.w = ex[4*j+3]*inv;
    *(float4*)(rp + base) = o;
  }
}

extern "C" void kernel_launch(void* const* d_in, const int* in_sizes, int n_in,
                              void* d_out, int out_size, void* d_ws, size_t ws_size,
                              hipStream_t stream) {
  (void)in_sizes; (void)n_in; (void)out_size; (void)ws_size;
  const float* q     = (const float*)d_in[0];
  const float* k     = (const float*)d_in[1];
  const float* v     = (const float*)d_in[2];
  const int*   mask  = (const int*)d_in[3];
  const float* qmask = (const float*)d_in[4];
  const float* Wq    = (const float*)d_in[5];
  const float* Wk    = (const float*)d_in[6];
  const float* Wv    = (const float*)d_in[7];
  const float* Wfc   = (const float*)d_in[8];

  float* out   = (float*)d_out;                 // [2,2048,512]
  float* probs = out + 2097152;                 // [2,8,2048,2048] (logits then probs, in place)

  char* ws = (char*)d_ws;
  float*          qp    = (float*)(ws + 0);             // [B,H,Lq,64] (pre-scaled by 1/8)
  float*          kp    = (float*)(ws + 8388608);       // [B,H,Lk,64]
  unsigned short* vpT   = (unsigned short*)(ws + 16777216);  // [B,H,512,2048] bf16
  unsigned short* mixed = (unsigned short*)(ws + 50331648);  // [4096,4096] bf16
  float*          WqT   = (float*)(ws + 83886080);      // [512,512]
  float*          WkT   = (float*)(ws + 84934656);      // [512,512]
  unsigned short* WvT   = (unsigned short*)(ws + 85983232);  // [4096,512] bf16
  unsigned short* WfcT  = (unsigned short*)(ws + 90177536);  // [512,4096] bf16

  transpose_k<0><<<dim3(16, 16),  256, 0, stream>>>(Wq,  WqT,  512, 512);
  transpose_k<0><<<dim3(16, 16),  256, 0, stream>>>(Wk,  WkT,  512, 512);
  transpose_k<1><<<dim3(128, 16), 256, 0, stream>>>(Wv,  WvT,  512, 4096);
  transpose_k<1><<<dim3(16, 128), 256, 0, stream>>>(Wfc, WfcT, 4096, 512);

  // fp32 projections (top-k path must be fp32-exact)
  gemm_f32_abt<0><<<dim3(8, 64), 256, 0, stream>>>(q, WqT, qp, 4096, 512, 512, 0.125f);
  gemm_f32_abt<0><<<dim3(8, 64), 256, 0, stream>>>(k, WkT, kp, 4096, 512, 512, 1.0f);

  // v_proj in bf16 MFMA, stored transposed per (b,h): [512,2048]
  gemm_bf16<float, 0><<<dim3(32, 64), 256, 0, stream>>>(v, WvT, vpT, 4096, 4096, 512);

  // fp32 logits into probs region (per (b,h) slice)
  gemm_f32_abt<1><<<dim3(32, 32, 16), 256, 0, stream>>>(qp, kp, probs, 2048, 2048, 64, 1.0f);

  // exact top-64 + softmax, in place
  topk_softmax_k<<<dim3(8192), 256, 0, stream>>>(probs, mask, qmask);

  // PV: probs (f32->bf16 at staging) x vpT -> mixed bf16
  gemm_bf16<float, 1><<<dim3(4, 32, 16), 256, 0, stream>>>(probs, vpT, mixed, 2048, 512, 2048);

  // fc: mixed x WfcT -> output f32
  gemm_bf16<unsigned short, 2><<<dim3(4, 64), 256, 0, stream>>>(mixed, WfcT, out, 4096, 512, 4096);
}

// Round 2
// 588.738 us; speedup vs baseline: 1.2715x; 1.2715x over previous
//
#include <hip/hip_runtime.h>
#include <stdint.h>

#define NEGF  (-3.402823466e38f)
#define TOPK  64

typedef __attribute__((ext_vector_type(8))) short bfrag8;
typedef __attribute__((ext_vector_type(4))) float f32x4;
typedef __attribute__((ext_vector_type(16))) float f32x16;

static __device__ __forceinline__ unsigned short f2bf(float f) {
  union { float f; unsigned u; } c; c.f = f;
  unsigned u = c.u;
  return (unsigned short)((u + 0x7fffu + ((u >> 16) & 1u)) >> 16);
}
static __device__ __forceinline__ unsigned mono(float x) {
  union { float f; unsigned u; } c; c.f = x;
  return (c.u & 0x80000000u) ? ~c.u : (c.u | 0x80000000u);
}
static __device__ __forceinline__ float invmono(unsigned k) {
  union { unsigned u; float f; } c;
  c.u = (k & 0x80000000u) ? (k ^ 0x80000000u) : ~k;
  return c.f;
}
static __device__ __forceinline__ int waveSum(int v) {
  #pragma unroll
  for (int o = 1; o < 64; o <<= 1) v += __shfl_xor(v, o);
  return v;
}
static __device__ __forceinline__ float waveSumF(float v) {
  #pragma unroll
  for (int o = 1; o < 64; o <<= 1) v += __shfl_xor(v, o);
  return v;
}
static __device__ __forceinline__ unsigned waveMaxU(unsigned v) {
  #pragma unroll
  for (int o = 1; o < 64; o <<= 1) {
    unsigned t = (unsigned)__shfl_xor((int)v, o);
    v = v > t ? v : t;
  }
  return v;
}

// ---------------- transpose: in f32 [R][C] -> out (f32 or bf16) [C][R] ----------------
template<int OBF>
__global__ __launch_bounds__(256) void transpose_k(const float* __restrict__ in,
                                                   void* __restrict__ out, int R, int C) {
  __shared__ float t[32][33];
  int c0 = blockIdx.x * 32, r0 = blockIdx.y * 32;
  int tx = threadIdx.x & 31, ty = (threadIdx.x >> 5) * 4;
  #pragma unroll
  for (int i = 0; i < 4; i++)
    t[ty + i][tx] = in[(size_t)(r0 + ty + i) * C + c0 + tx];
  __syncthreads();
  #pragma unroll
  for (int i = 0; i < 4; i++) {
    float v = t[tx][ty + i];
    size_t idx = (size_t)(c0 + ty + i) * R + r0 + tx;
    if (OBF) ((unsigned short*)out)[idx] = f2bf(v);
    else     ((float*)out)[idx] = v;
  }
}

// ---------------- fp32 GEMM for q/k projections: C = A[M,K] x Bt[N,K]^T ----------------
// epilogue: m->(b=m>>11,l), n->(h=n>>6,dd); out[((b*8+h)*2048+l)*64+dd]=acc*scale
__global__ __launch_bounds__(256) void gemm_f32_abt(const float* __restrict__ A,
    const float* __restrict__ Bt, float* __restrict__ C,
    int M, int N, int K, float scale) {
  __shared__ float As[64][65];
  __shared__ float Bs[64][65];
  int tid = threadIdx.x;
  int tx = tid & 15, ty = tid >> 4;
  int m0 = blockIdx.y * 64, n0 = blockIdx.x * 64;
  float acc[4][4] = {};
  for (int k0 = 0; k0 < K; k0 += 64) {
    #pragma unroll
    for (int i = 0; i < 4; i++) {
      int f = tid + (i << 8);
      int row = f >> 4, kc = (f & 15) << 2;
      float4 av = *(const float4*)(A + (size_t)(m0 + row) * K + k0 + kc);
      As[row][kc+0] = av.x; As[row][kc+1] = av.y; As[row][kc+2] = av.z; As[row][kc+3] = av.w;
      float4 bv = *(const float4*)(Bt + (size_t)(n0 + row) * K + k0 + kc);
      Bs[row][kc+0] = bv.x; Bs[row][kc+1] = bv.y; Bs[row][kc+2] = bv.z; Bs[row][kc+3] = bv.w;
    }
    __syncthreads();
    #pragma unroll 4
    for (int d = 0; d < 64; d++) {
      float a[4], b[4];
      #pragma unroll
      for (int i = 0; i < 4; i++) a[i] = As[ty*4 + i][d];
      #pragma unroll
      for (int j = 0; j < 4; j++) b[j] = Bs[tx*4 + j][d];
      #pragma unroll
      for (int i = 0; i < 4; i++)
        #pragma unroll
        for (int j = 0; j < 4; j++)
          acc[i][j] = fmaf(a[i], b[j], acc[i][j]);
    }
    __syncthreads();
  }
  #pragma unroll
  for (int i = 0; i < 4; i++) {
    int m = m0 + ty*4 + i;
    float4 v4;
    v4.x = acc[i][0]*scale; v4.y = acc[i][1]*scale; v4.z = acc[i][2]*scale; v4.w = acc[i][3]*scale;
    int b = m >> 11, l = m & 2047;
    int n = n0 + tx*4;
    int h = n >> 6, dd = n & 63;
    *(float4*)(C + ((((size_t)b*8 + h)*2048 + l)*64 + dd)) = v4;
  }
}

// ---------------- fp32 logits GEMM, K=64 single-stage, fused mask ----------------
// grid (16 nb, 16 mb, 16 z), 256 thr. Tile 128x128, per-thread 8x8.
// out[z][m][n] = (mask[b][m][n]==0) ? NEG : qp[z][m]·kp[z][n]
__global__ __launch_bounds__(256) void logits_mask_kernel(
    const float* __restrict__ qp, const float* __restrict__ kp,
    const int* __restrict__ mask, float* __restrict__ out) {
  __shared__ float AsT[64][132];   // [k][m]
  __shared__ float BsT[64][132];   // [k][n]
  int tid = threadIdx.x;
  int z = blockIdx.z, b = z >> 3;
  int m0 = blockIdx.y * 128, n0 = blockIdx.x * 128;
  const float* Ap = qp + (size_t)z * (2048 * 64);
  const float* Bp = kp + (size_t)z * (2048 * 64);
  {
    int rr = tid >> 2;            // 0..63
    int kq = (tid & 3) << 2;      // 0,4,8,12  (+16*s)
    #pragma unroll
    for (int pass = 0; pass < 2; pass++) {
      int r = rr + (pass << 6);
      const float* ar = Ap + (size_t)(m0 + r) * 64 + kq;
      const float* br = Bp + (size_t)(n0 + r) * 64 + kq;
      #pragma unroll
      for (int s = 0; s < 4; s++) {
        float4 av = *(const float4*)(ar + (s << 4));
        float4 bv = *(const float4*)(br + (s << 4));
        int k = kq + (s << 4);
        AsT[k+0][r] = av.x; AsT[k+1][r] = av.y; AsT[k+2][r] = av.z; AsT[k+3][r] = av.w;
        BsT[k+0][r] = bv.x; BsT[k+1][r] = bv.y; BsT[k+2][r] = bv.z; BsT[k+3][r] = bv.w;
      }
    }
  }
  __syncthreads();
  int lane = tid & 63, w = tid >> 6;
  int lx = lane & 15, ly = lane >> 4;
  int ra = w * 32 + ly * 4;        // rows ra..ra+3, ra+16..ra+19
  int ca = lx * 4;                 // cols ca..ca+3, ca+64..ca+67
  float acc[8][8] = {};
  #pragma unroll 2
  for (int d = 0; d < 64; d++) {
    f32x4 a0 = *(const f32x4*)&AsT[d][ra];
    f32x4 a1 = *(const f32x4*)&AsT[d][ra + 16];
    f32x4 b0 = *(const f32x4*)&BsT[d][ca];
    f32x4 b1 = *(const f32x4*)&BsT[d][ca + 64];
    float a[8] = {a0[0],a0[1],a0[2],a0[3],a1[0],a1[1],a1[2],a1[3]};
    float bb[8] = {b0[0],b0[1],b0[2],b0[3],b1[0],b1[1],b1[2],b1[3]};
    #pragma unroll
    for (int i = 0; i < 8; i++)
      #pragma unroll
      for (int j = 0; j < 8; j++)
        acc[i][j] = fmaf(a[i], bb[j], acc[i][j]);
  }
  size_t outbase = (size_t)z * 2048 * 2048;
  const int* mbase = mask + (size_t)b * 2048 * 2048;
  #pragma unroll
  for (int i = 0; i < 8; i++) {
    int row = m0 + ra + (i & 3) + ((i >> 2) << 4);
    const int* mp = mbase + (size_t)row * 2048 + n0;
    float* op = out + outbase + (size_t)row * 2048 + n0;
    int4 mv0 = *(const int4*)(mp + ca);
    int4 mv1 = *(const int4*)(mp + ca + 64);
    float4 o0, o1;
    o0.x = mv0.x ? acc[i][0] : NEGF;
    o0.y = mv0.y ? acc[i][1] : NEGF;
    o0.z = mv0.z ? acc[i][2] : NEGF;
    o0.w = mv0.w ? acc[i][3] : NEGF;
    o1.x = mv1.x ? acc[i][4] : NEGF;
    o1.y = mv1.y ? acc[i][5] : NEGF;
    o1.z = mv1.z ? acc[i][6] : NEGF;
    o1.w = mv1.w ? acc[i][7] : NEGF;
    *(float4*)(op + ca) = o0;
    *(float4*)(op + ca + 64) = o1;
  }
}

// ---------------- bf16 MFMA GEMM (v_proj / fc), unchanged ----------------
template<typename AT, int MODE>
__global__ __launch_bounds__(256) void gemm_bf16(const AT* __restrict__ A,
    const unsigned short* __restrict__ Bt, void* __restrict__ Cout,
    int M, int N, int K) {
  __shared__ unsigned short As[64][72];
  __shared__ unsigned short Bs[128][72];
  int tid = threadIdx.x;
  int lane = tid & 63, wave = tid >> 6;
  int wr = wave >> 1, wc = wave & 1;
  int m0 = blockIdx.y * 64, n0 = blockIdx.x * 128;
  f32x4 acc[2][4];
  #pragma unroll
  for (int mi = 0; mi < 2; mi++)
    #pragma unroll
    for (int ni = 0; ni < 4; ni++) acc[mi][ni] = (f32x4){0.f, 0.f, 0.f, 0.f};
  int arow = tid >> 2, akc = (tid & 3) << 4;
  int brow = tid >> 1, bkc = (tid & 1) << 5;
  for (int k0 = 0; k0 < K; k0 += 64) {
    {
      const AT* src = A + (size_t)(m0 + arow) * K + k0 + akc;
      if constexpr (sizeof(AT) == 4) {
        const float* s = (const float*)src;
        float4 x0 = *(const float4*)(s + 0);
        float4 x1 = *(const float4*)(s + 4);
        float4 x2 = *(const float4*)(s + 8);
        float4 x3 = *(const float4*)(s + 12);
        union { bfrag8 v; unsigned short u[8]; } p0, p1;
        p0.u[0]=f2bf(x0.x); p0.u[1]=f2bf(x0.y); p0.u[2]=f2bf(x0.z); p0.u[3]=f2bf(x0.w);
        p0.u[4]=f2bf(x1.x); p0.u[5]=f2bf(x1.y); p0.u[6]=f2bf(x1.z); p0.u[7]=f2bf(x1.w);
        p1.u[0]=f2bf(x2.x); p1.u[1]=f2bf(x2.y); p1.u[2]=f2bf(x2.z); p1.u[3]=f2bf(x2.w);
        p1.u[4]=f2bf(x3.x); p1.u[5]=f2bf(x3.y); p1.u[6]=f2bf(x3.z); p1.u[7]=f2bf(x3.w);
        *(bfrag8*)&As[arow][akc + 0] = p0.v;
        *(bfrag8*)&As[arow][akc + 8] = p1.v;
      } else {
        const bfrag8* s = (const bfrag8*)src;
        *(bfrag8*)&As[arow][akc + 0] = s[0];
        *(bfrag8*)&As[arow][akc + 8] = s[1];
      }
    }
    {
      const bfrag8* s = (const bfrag8*)(Bt + (size_t)(n0 + brow) * K + k0 + bkc);
      #pragma unroll
      for (int j = 0; j < 4; j++)
        *(bfrag8*)&Bs[brow][bkc + 8*j] = s[j];
    }
    __syncthreads();
    #pragma unroll
    for (int kh = 0; kh < 2; kh++) {
      int krd = (kh << 5) + ((lane >> 4) << 3);
      bfrag8 af[2], bfr[4];
      #pragma unroll
      for (int mi = 0; mi < 2; mi++)
        af[mi] = *(const bfrag8*)&As[wr*32 + mi*16 + (lane & 15)][krd];
      #pragma unroll
      for (int ni = 0; ni < 4; ni++)
        bfr[ni] = *(const bfrag8*)&Bs[wc*64 + ni*16 + (lane & 15)][krd];
      #pragma unroll
      for (int mi = 0; mi < 2; mi++)
        #pragma unroll
        for (int ni = 0; ni < 4; ni++)
          acc[mi][ni] = __builtin_amdgcn_mfma_f32_16x16x32_bf16(af[mi], bfr[ni], acc[mi][ni], 0, 0, 0);
    }
    __syncthreads();
  }
  #pragma unroll
  for (int mi = 0; mi < 2; mi++) {
    int rb = m0 + wr*32 + mi*16 + ((lane >> 4) << 2);
    #pragma unroll
    for (int ni = 0; ni < 4; ni++) {
      int col = n0 + wc*64 + ni*16 + (lane & 15);
      f32x4 v = acc[mi][ni];
      if (MODE == 0) {
        int b = rb >> 11, l = rb & 2047;
        int h = col >> 9, d = col & 511;
        unsigned short* o = (unsigned short*)Cout + ((((size_t)b*8 + h)*512 + d)*2048 + l);
        ushort4 u;
        u.x = f2bf(v[0]); u.y = f2bf(v[1]); u.z = f2bf(v[2]); u.w = f2bf(v[3]);
        *(ushort4*)o = u;
      } else {
        float* o = (float*)Cout;
        #pragma unroll
        for (int j = 0; j < 4; j++)
          o[(size_t)(rb + j)*512 + col] = v[j];
      }
    }
  }
}

// ---------------- PV: probs[z][2048][2048] f32 x vpT[z][512][2048] -> mixed bf16 ----------------
// grid (1, 32, 16), 512 thr (8 waves). BM=64, BN=512, BK=64. Wave tile 64x64 via 32x32x16 MFMA.
// LDS rows 128B, chunk rotation p=(c+n)&7 -> conflict-free b128, no padding.
__global__ __launch_bounds__(512) void pv_kernel(const float* __restrict__ probs,
    const unsigned short* __restrict__ vpT, unsigned short* __restrict__ mixed) {
  __shared__ unsigned short As[64][64];
  __shared__ unsigned short Bs[512][64];
  int tid = threadIdx.x;
  int lane = tid & 63, wv = tid >> 6;
  int l31 = lane & 31, lh = lane >> 5;
  int z = blockIdx.z, m0 = blockIdx.y * 64;
  const float* Ap = probs + (size_t)z * 2048 * 2048 + (size_t)m0 * 2048;
  const unsigned short* Bp = vpT + (size_t)z * 512 * 2048;
  f32x16 acc[2][2];
  #pragma unroll
  for (int mf = 0; mf < 2; mf++)
    #pragma unroll
    for (int nf = 0; nf < 2; nf++)
      #pragma unroll
      for (int r = 0; r < 16; r++) acc[mf][nf][r] = 0.f;
  int a_r = tid >> 3, a_c = tid & 7;
  for (int k0 = 0; k0 < 2048; k0 += 64) {
    { // stage A: 64x64 f32 -> bf16
      const float* s = Ap + (size_t)a_r * 2048 + k0 + a_c * 8;
      float4 x0 = *(const float4*)s;
      float4 x1 = *(const float4*)(s + 4);
      union { bfrag8 v; unsigned short u[8]; } p;
      p.u[0]=f2bf(x0.x); p.u[1]=f2bf(x0.y); p.u[2]=f2bf(x0.z); p.u[3]=f2bf(x0.w);
      p.u[4]=f2bf(x1.x); p.u[5]=f2bf(x1.y); p.u[6]=f2bf(x1.z); p.u[7]=f2bf(x1.w);
      *(bfrag8*)&As[a_r][((a_c + a_r) & 7) * 8] = p.v;
    }
    #pragma unroll
    for (int s = 0; s < 8; s++) { // stage B: 512x64 bf16
      int n = (tid >> 3) + (s << 6);
      bfrag8 vb = *(const bfrag8*)(Bp + (size_t)n * 2048 + k0 + a_c * 8);
      *(bfrag8*)&Bs[n][((a_c + n) & 7) * 8] = vb;
    }
    __syncthreads();
    #pragma unroll
    for (int ks = 0; ks < 4; ks++) {
      int qd = ks * 2 + lh;
      bfrag8 af[2], bfr[2];
      #pragma unroll
      for (int mf = 0; mf < 2; mf++) {
        int r = mf * 32 + l31;
        af[mf] = *(const bfrag8*)&As[r][((qd + r) & 7) * 8];
      }
      #pragma unroll
      for (int nf = 0; nf < 2; nf++) {
        int n = wv * 64 + nf * 32 + l31;
        bfr[nf] = *(const bfrag8*)&Bs[n][((qd + n) & 7) * 8];
      }
      #pragma unroll
      for (int mf = 0; mf < 2; mf++)
        #pragma unroll
        for (int nf = 0; nf < 2; nf++)
          acc[mf][nf] = __builtin_amdgcn_mfma_f32_32x32x16_bf16(af[mf], bfr[nf], acc[mf][nf], 0, 0, 0);
    }
    __syncthreads();
  }
  int bb = z >> 3, h = z & 7;
  #pragma unroll
  for (int mf = 0; mf < 2; mf++)
    #pragma unroll
    for (int nf = 0; nf < 2; nf++) {
      int n = wv * 64 + nf * 32 + l31;
      #pragma unroll
      for (int r = 0; r < 16; r++) {
        int row = m0 + mf * 32 + (r & 3) + ((r >> 2) << 3) + (lh << 2);
        mixed[((size_t)bb * 2048 + row) * 4096 + h * 512 + n] = f2bf(acc[mf][nf][r]);
      }
    }
}

// ---------------- per-row top-k + softmax (one wave per row, in-place) ----------------
// logits are pre-masked (NEG where mask==0). hi16 binary search + exact candidate extract.
__global__ __launch_bounds__(256) void topk_softmax_k(float* __restrict__ probs,
    const float* __restrict__ qmaskf) {
  int lane = threadIdx.x & 63;
  int row = blockIdx.x * 4 + (threadIdx.x >> 6);   // (b*8+h)*2048 + q
  int b = row >> 14, q = row & 2047;
  float* rp = probs + (size_t)row * 2048;
  unsigned key[32];
  #pragma unroll
  for (int j = 0; j < 8; j++) {
    int base = (lane << 2) + (j << 8);
    float4 v = *(const float4*)(rp + base);
    key[4*j+0] = mono(v.x);
    key[4*j+1] = mono(v.y);
    key[4*j+2] = mono(v.z);
    key[4*j+3] = mono(v.w);
  }
  unsigned drop = 0;
  bool qm = qmaskf[b * 2048 + q] > 0.5f;
  if (qm) {
    // 1) binary search on high 16 bits (16 iterations)
    unsigned lo = 0u, hi = 0xFFFFu;
    while (lo < hi) {
      unsigned mid = lo + ((hi - lo + 1u) >> 1);
      unsigned t = mid << 16;
      int c = 0;
      #pragma unroll
      for (int e = 0; e < 32; e++) c += (key[e] >= t) ? 1 : 0;
      c = waveSum(c);
      if (c >= TOPK) lo = mid; else hi = mid - 1u;
    }
    unsigned P = lo;
    unsigned hiMax = (P << 16) | 0xFFFFu;
    // 2) exact K64 among candidates with hi16==P
    int cgt_hi = 0;
    #pragma unroll
    for (int e = 0; e < 32; e++) cgt_hi += (key[e] > hiMax) ? 1 : 0;
    cgt_hi = waveSum(cgt_hi);
    int remaining = TOPK - cgt_hi;
    unsigned cur = 0xFFFFFFFFu;
    unsigned K64 = P << 16;
    for (;;) {
      unsigned mx = 0;
      #pragma unroll
      for (int e = 0; e < 32; e++) {
        unsigned kk = key[e];
        if ((kk >> 16) == P && kk < cur) mx = mx > kk ? mx : kk;
      }
      mx = waveMaxU(mx);
      int ce = 0;
      #pragma unroll
      for (int e = 0; e < 32; e++) ce += (key[e] == mx) ? 1 : 0;
      ce = waveSum(ce);
      if (remaining <= ce) { K64 = mx; break; }
      remaining -= ce;
      cur = mx;
    }
    // 3) build drop mask
    int cgt = 0, ceq = 0;
    #pragma unroll
    for (int e = 0; e < 32; e++) { cgt += (key[e] > K64) ? 1 : 0; ceq += (key[e] == K64) ? 1 : 0; }
    cgt = waveSum(cgt);
    int ceqT = waveSum(ceq);
    int r = TOPK - cgt;
    #pragma unroll
    for (int e = 0; e < 32; e++) if (key[e] < K64) drop |= (1u << e);
    if (ceqT > r) {
      int taken = 0;
      for (int j = 0; j < 8; j++) {
        int cl = 0, eqm = 0;
        #pragma unroll
        for (int t = 0; t < 4; t++)
          if (key[4*j+t] == K64) { eqm |= (1 << t); cl++; }
        int incl = cl;
        for (int o = 1; o < 64; o <<= 1) {
          int tt = __shfl_up(incl, o);
          if (lane >= o) incl += tt;
        }
        int pref = incl - cl;
        int tot = __shfl(incl, 63);
        int rk = taken + pref;
        #pragma unroll
        for (int t = 0; t < 4; t++) {
          if ((eqm >> t) & 1) {
            if (rk >= r) drop |= (1u << (4*j+t));
            rk++;
          }
        }
        taken += tot;
      }
    }
  }
  unsigned kmax = 0;
  #pragma unroll
  for (int e = 0; e < 32; e++)
    if (!((drop >> e) & 1u)) kmax = kmax > key[e] ? kmax : key[e];
  kmax = waveMaxU(kmax);
  float mx = invmono(kmax);
  float ex[32]; float s = 0.f;
  #pragma unroll
  for (int e = 0; e < 32; e++) {
    float t = ((drop >> e) & 1u) ? 0.f : __expf(invmono(key[e]) - mx);
    ex[e] = t; s += t;
  }
  s = waveSumF(s);
  float inv = 1.0f / s;
  #pragma unroll
  for (int j = 0; j < 8; j++) {
    int base = (lane << 2) + (j << 8);
    float4 o;
    o.x = ex[4*j+0]*inv; o.y = ex[4*j+1]*inv; o.z = ex[4*j+2]*inv; o.w = ex[4*j+3]*inv;
    *(float4*)(rp + base) = o;
  }
}

extern "C" void kernel_launch(void* const* d_in, const int* in_sizes, int n_in,
                              void* d_out, int out_size, void* d_ws, size_t ws_size,
                              hipStream_t stream) {
  (void)in_sizes; (void)n_in; (void)out_size; (void)ws_size;
  const float* q     = (const float*)d_in[0];
  const float* k     = (const float*)d_in[1];
  const float* v     = (const float*)d_in[2];
  const int*   mask  = (const int*)d_in[3];
  const float* qmask = (const float*)d_in[4];
  const float* Wq    = (const float*)d_in[5];
  const float* Wk    = (const float*)d_in[6];
  const float* Wv    = (const float*)d_in[7];
  const float* Wfc   = (const float*)d_in[8];

  float* out   = (float*)d_out;                 // [2,2048,512]
  float* probs = out + 2097152;                 // [2,8,2048,2048] (logits then probs, in place)

  char* ws = (char*)d_ws;
  float*          qp    = (float*)(ws + 0);             // [B,H,Lq,64] (pre-scaled by 1/8)
  float*          kp    = (float*)(ws + 8388608);       // [B,H,Lk,64]
  unsigned short* vpT   = (unsigned short*)(ws + 16777216);  // [B,H,512,2048] bf16
  unsigned short* mixed = (unsigned short*)(ws + 50331648);  // [4096,4096] bf16
  float*          WqT   = (float*)(ws + 83886080);      // [512,512]
  float*          WkT   = (float*)(ws + 84934656);      // [512,512]
  unsigned short* WvT   = (unsigned short*)(ws + 85983232);  // [4096,512] bf16
  unsigned short* WfcT  = (unsigned short*)(ws + 90177536);  // [512,4096] bf16

  transpose_k<0><<<dim3(16, 16),  256, 0, stream>>>(Wq,  WqT,  512, 512);
  transpose_k<0><<<dim3(16, 16),  256, 0, stream>>>(Wk,  WkT,  512, 512);
  transpose_k<1><<<dim3(128, 16), 256, 0, stream>>>(Wv,  WvT,  512, 4096);
  transpose_k<1><<<dim3(16, 128), 256, 0, stream>>>(Wfc, WfcT, 4096, 512);

  // fp32 projections (top-k path must be fp32-exact)
  gemm_f32_abt<<<dim3(8, 64), 256, 0, stream>>>(q, WqT, qp, 4096, 512, 512, 0.125f);
  gemm_f32_abt<<<dim3(8, 64), 256, 0, stream>>>(k, WkT, kp, 4096, 512, 512, 1.0f);

  // v_proj in bf16 MFMA, stored transposed per (b,h): [512,2048]
  gemm_bf16<float, 0><<<dim3(32, 64), 256, 0, stream>>>(v, WvT, vpT, 4096, 4096, 512);

  // fp32 logits with fused post-softmax mask -> probs region
  logits_mask_kernel<<<dim3(16, 16, 16), 256, 0, stream>>>(qp, kp, mask, probs);

  // exact top-64 + softmax, in place
  topk_softmax_k<<<dim3(8192), 256, 0, stream>>>(probs, qmask);

  // PV: probs (f32->bf16 at staging) x vpT -> mixed bf16
  pv_kernel<<<dim3(1, 32, 16), 512, 0, stream>>>(probs, vpT, mixed);

  // fc: mixed x WfcT -> output f32
  gemm_bf16<unsigned short, 2><<<dim3(4, 64), 256, 0, stream>>>(mixed, WfcT, out, 4096, 512, 4096);
}

// Round 3
// 580.961 us; speedup vs baseline: 1.2885x; 1.0134x over previous
//
#include <hip/hip_runtime.h>
#include <stdint.h>

#define NEGF  (-3.402823466e38f)
#define TOPK  64

typedef __attribute__((ext_vector_type(8))) short bfrag8;
typedef __attribute__((ext_vector_type(4))) float f32x4;
typedef __attribute__((ext_vector_type(16))) float f32x16;

static __device__ __forceinline__ unsigned short f2bf(float f) {
  union { float f; unsigned u; } c; c.f = f;
  unsigned u = c.u;
  return (unsigned short)((u + 0x7fffu + ((u >> 16) & 1u)) >> 16);
}
static __device__ __forceinline__ unsigned mono(float x) {
  union { float f; unsigned u; } c; c.f = x;
  return (c.u & 0x80000000u) ? ~c.u : (c.u | 0x80000000u);
}
static __device__ __forceinline__ float invmono(unsigned k) {
  union { unsigned u; float f; } c;
  c.u = (k & 0x80000000u) ? (k ^ 0x80000000u) : ~k;
  return c.f;
}
static __device__ __forceinline__ int waveSum(int v) {
  #pragma unroll
  for (int o = 1; o < 64; o <<= 1) v += __shfl_xor(v, o);
  return v;
}
static __device__ __forceinline__ float waveSumF(float v) {
  #pragma unroll
  for (int o = 1; o < 64; o <<= 1) v += __shfl_xor(v, o);
  return v;
}
static __device__ __forceinline__ unsigned waveMaxU(unsigned v) {
  #pragma unroll
  for (int o = 1; o < 64; o <<= 1) {
    unsigned t = (unsigned)__shfl_xor((int)v, o);
    v = v > t ? v : t;
  }
  return v;
}

// ---------------- transpose: in f32 [R][C] -> out (f32 or bf16) [C][R] ----------------
template<int OBF>
__global__ __launch_bounds__(256) void transpose_k(const float* __restrict__ in,
                                                   void* __restrict__ out, int R, int C) {
  __shared__ float t[32][33];
  int c0 = blockIdx.x * 32, r0 = blockIdx.y * 32;
  int tx = threadIdx.x & 31, ty = (threadIdx.x >> 5) * 4;
  #pragma unroll
  for (int i = 0; i < 4; i++)
    t[ty + i][tx] = in[(size_t)(r0 + ty + i) * C + c0 + tx];
  __syncthreads();
  #pragma unroll
  for (int i = 0; i < 4; i++) {
    float v = t[tx][ty + i];
    size_t idx = (size_t)(c0 + ty + i) * R + r0 + tx;
    if (OBF) ((unsigned short*)out)[idx] = f2bf(v);
    else     ((float*)out)[idx] = v;
  }
}

// ---------------- fp32 projection GEMM (q & k merged), 128x128 tile, k-major LDS ----------------
// grid (4 nb, 32 mb, 2 z). z=0: qp from q,WqT (scale 1/8); z=1: kp from k,WkT (scale 1).
// epilogue: m->(b=m>>11,l), n->(h=n>>6,dd); out[((b*8+h)*2048+l)*64+dd]=acc*scale
__global__ __launch_bounds__(256) void proj_f32_kernel(
    const float* __restrict__ q, const float* __restrict__ k,
    const float* __restrict__ WqT, const float* __restrict__ WkT,
    float* __restrict__ qp, float* __restrict__ kp) {
  __shared__ float AsT[64][132];   // [k][m]
  __shared__ float BsT[64][132];   // [k][n]
  int tid = threadIdx.x;
  int z = blockIdx.z;
  const float* A  = z ? k : q;
  const float* Bt = z ? WkT : WqT;
  float* out      = z ? kp : qp;
  float scale     = z ? 1.0f : 0.125f;
  int m0 = blockIdx.y * 128, n0 = blockIdx.x * 128;
  int lane = tid & 63, w = tid >> 6;
  int lx = lane & 15, ly = lane >> 4;
  int ra = w * 32 + ly * 4;
  int ca = lx * 4;
  int rr = tid >> 1;               // 0..127
  int kq0 = (tid & 1) << 5;        // 0 or 32
  float acc[8][8] = {};
  for (int k0 = 0; k0 < 512; k0 += 64) {
    const float* ar = A  + (size_t)(m0 + rr) * 512 + k0 + kq0;
    const float* br = Bt + (size_t)(n0 + rr) * 512 + k0 + kq0;
    #pragma unroll
    for (int s = 0; s < 8; s++) {
      float4 av = *(const float4*)(ar + (s << 2));
      float4 bv = *(const float4*)(br + (s << 2));
      int kk = kq0 + (s << 2);
      AsT[kk+0][rr] = av.x; AsT[kk+1][rr] = av.y; AsT[kk+2][rr] = av.z; AsT[kk+3][rr] = av.w;
      BsT[kk+0][rr] = bv.x; BsT[kk+1][rr] = bv.y; BsT[kk+2][rr] = bv.z; BsT[kk+3][rr] = bv.w;
    }
    __syncthreads();
    #pragma unroll 2
    for (int d = 0; d < 64; d++) {
      f32x4 a0 = *(const f32x4*)&AsT[d][ra];
      f32x4 a1 = *(const f32x4*)&AsT[d][ra + 16];
      f32x4 b0 = *(const f32x4*)&BsT[d][ca];
      f32x4 b1 = *(const f32x4*)&BsT[d][ca + 64];
      float a[8] = {a0[0],a0[1],a0[2],a0[3],a1[0],a1[1],a1[2],a1[3]};
      float bb[8] = {b0[0],b0[1],b0[2],b0[3],b1[0],b1[1],b1[2],b1[3]};
      #pragma unroll
      for (int i = 0; i < 8; i++)
        #pragma unroll
        for (int j = 0; j < 8; j++)
          acc[i][j] = fmaf(a[i], bb[j], acc[i][j]);
    }
    __syncthreads();
  }
  #pragma unroll
  for (int i = 0; i < 8; i++) {
    int m = m0 + ra + (i & 3) + ((i >> 2) << 4);
    int b = m >> 11, l = m & 2047;
    #pragma unroll
    for (int half = 0; half < 2; half++) {
      int n = n0 + ca + half * 64;
      int h = n >> 6, dd = n & 63;
      float4 v4;
      v4.x = acc[i][half*4+0]*scale; v4.y = acc[i][half*4+1]*scale;
      v4.z = acc[i][half*4+2]*scale; v4.w = acc[i][half*4+3]*scale;
      *(float4*)(out + ((((size_t)b*8 + h)*2048 + l)*64 + dd)) = v4;
    }
  }
}

// ---------------- fp32 logits GEMM, K=64 single-stage, fused mask ----------------
__global__ __launch_bounds__(256) void logits_mask_kernel(
    const float* __restrict__ qp, const float* __restrict__ kp,
    const int* __restrict__ mask, float* __restrict__ out) {
  __shared__ float AsT[64][132];   // [k][m]
  __shared__ float BsT[64][132];   // [k][n]
  int tid = threadIdx.x;
  int z = blockIdx.z, b = z >> 3;
  int m0 = blockIdx.y * 128, n0 = blockIdx.x * 128;
  const float* Ap = qp + (size_t)z * (2048 * 64);
  const float* Bp = kp + (size_t)z * (2048 * 64);
  {
    int rr = tid >> 2;
    int kq = (tid & 3) << 2;
    #pragma unroll
    for (int pass = 0; pass < 2; pass++) {
      int r = rr + (pass << 6);
      const float* ar = Ap + (size_t)(m0 + r) * 64 + kq;
      const float* br = Bp + (size_t)(n0 + r) * 64 + kq;
      #pragma unroll
      for (int s = 0; s < 4; s++) {
        float4 av = *(const float4*)(ar + (s << 4));
        float4 bv = *(const float4*)(br + (s << 4));
        int k = kq + (s << 4);
        AsT[k+0][r] = av.x; AsT[k+1][r] = av.y; AsT[k+2][r] = av.z; AsT[k+3][r] = av.w;
        BsT[k+0][r] = bv.x; BsT[k+1][r] = bv.y; BsT[k+2][r] = bv.z; BsT[k+3][r] = bv.w;
      }
    }
  }
  __syncthreads();
  int lane = tid & 63, w = tid >> 6;
  int lx = lane & 15, ly = lane >> 4;
  int ra = w * 32 + ly * 4;
  int ca = lx * 4;
  float acc[8][8] = {};
  #pragma unroll 2
  for (int d = 0; d < 64; d++) {
    f32x4 a0 = *(const f32x4*)&AsT[d][ra];
    f32x4 a1 = *(const f32x4*)&AsT[d][ra + 16];
    f32x4 b0 = *(const f32x4*)&BsT[d][ca];
    f32x4 b1 = *(const f32x4*)&BsT[d][ca + 64];
    float a[8] = {a0[0],a0[1],a0[2],a0[3],a1[0],a1[1],a1[2],a1[3]};
    float bb[8] = {b0[0],b0[1],b0[2],b0[3],b1[0],b1[1],b1[2],b1[3]};
    #pragma unroll
    for (int i = 0; i < 8; i++)
      #pragma unroll
      for (int j = 0; j < 8; j++)
        acc[i][j] = fmaf(a[i], bb[j], acc[i][j]);
  }
  size_t outbase = (size_t)z * 2048 * 2048;
  const int* mbase = mask + (size_t)b * 2048 * 2048;
  #pragma unroll
  for (int i = 0; i < 8; i++) {
    int row = m0 + ra + (i & 3) + ((i >> 2) << 4);
    const int* mp = mbase + (size_t)row * 2048 + n0;
    float* op = out + outbase + (size_t)row * 2048 + n0;
    int4 mv0 = *(const int4*)(mp + ca);
    int4 mv1 = *(const int4*)(mp + ca + 64);
    float4 o0, o1;
    o0.x = mv0.x ? acc[i][0] : NEGF;
    o0.y = mv0.y ? acc[i][1] : NEGF;
    o0.z = mv0.z ? acc[i][2] : NEGF;
    o0.w = mv0.w ? acc[i][3] : NEGF;
    o1.x = mv1.x ? acc[i][4] : NEGF;
    o1.y = mv1.y ? acc[i][5] : NEGF;
    o1.z = mv1.z ? acc[i][6] : NEGF;
    o1.w = mv1.w ? acc[i][7] : NEGF;
    *(float4*)(op + ca) = o0;
    *(float4*)(op + ca + 64) = o1;
  }
}

// ---------------- v_proj per-z: vpT[z][d][l] = sum_e WvT[h*512+d][e] * v[b][l][e] ----------------
// grid (16 nb, 4 mb, 16 z), 256 thr. BM=BN=128, BK=64, 4 waves 2x2, wave tile 64x64 (2x2 of 32x32x16).
// Both operands contiguous in K; chunk-rotation swizzle on LDS rows (128B).
__global__ __launch_bounds__(256) void vproj_kernel(const float* __restrict__ v,
    const unsigned short* __restrict__ WvT, unsigned short* __restrict__ vpT) {
  __shared__ unsigned short As[128][64];   // WvT tile [d][k], swizzled
  __shared__ unsigned short Bs[128][64];   // v tile [l][k] bf16, swizzled
  int tid = threadIdx.x;
  int lane = tid & 63, wv = tid >> 6;
  int l31 = lane & 31, lh = lane >> 5;
  int wr = wv >> 1, wc = wv & 1;
  int z = blockIdx.z, b = z >> 3, h = z & 7;
  int m0 = blockIdx.y * 128, n0 = blockIdx.x * 128;
  const unsigned short* Ap = WvT + (size_t)(h * 512 + m0) * 512;
  const float* Bp = v + ((size_t)b * 2048 + n0) * 512;
  f32x16 acc[2][2];
  #pragma unroll
  for (int mf = 0; mf < 2; mf++)
    #pragma unroll
    for (int nf = 0; nf < 2; nf++)
      #pragma unroll
      for (int r = 0; r < 16; r++) acc[mf][nf][r] = 0.f;
  int srow = tid >> 1;             // 0..127
  int skc = (tid & 1) << 5;        // 0 or 32 (bf16 elems)
  for (int k0 = 0; k0 < 512; k0 += 64) {
    { // stage A: 128x64 bf16
      const bfrag8* s = (const bfrag8*)(Ap + (size_t)srow * 512 + k0 + skc);
      #pragma unroll
      for (int j = 0; j < 4; j++) {
        int c = (skc >> 3) + j;
        *(bfrag8*)&As[srow][((c + srow) & 7) * 8] = s[j];
      }
    }
    { // stage B: 128x64 f32 -> bf16
      const float* s = Bp + (size_t)srow * 512 + k0 + skc;
      #pragma unroll
      for (int j = 0; j < 4; j++) {
        float4 x0 = *(const float4*)(s + 8*j);
        float4 x1 = *(const float4*)(s + 8*j + 4);
        union { bfrag8 v; unsigned short u[8]; } p;
        p.u[0]=f2bf(x0.x); p.u[1]=f2bf(x0.y); p.u[2]=f2bf(x0.z); p.u[3]=f2bf(x0.w);
        p.u[4]=f2bf(x1.x); p.u[5]=f2bf(x1.y); p.u[6]=f2bf(x1.z); p.u[7]=f2bf(x1.w);
        int c = (skc >> 3) + j;
        *(bfrag8*)&Bs[srow][((c + srow) & 7) * 8] = p.v;
      }
    }
    __syncthreads();
    #pragma unroll
    for (int ks = 0; ks < 4; ks++) {
      int qd = ks * 2 + lh;
      bfrag8 af[2], bfr[2];
      #pragma unroll
      for (int mf = 0; mf < 2; mf++) {
        int r = wr * 64 + mf * 32 + l31;
        af[mf] = *(const bfrag8*)&As[r][((qd + r) & 7) * 8];
      }
      #pragma unroll
      for (int nf = 0; nf < 2; nf++) {
        int n = wc * 64 + nf * 32 + l31;
        bfr[nf] = *(const bfrag8*)&Bs[n][((qd + n) & 7) * 8];
      }
      #pragma unroll
      for (int mf = 0; mf < 2; mf++)
        #pragma unroll
        for (int nf = 0; nf < 2; nf++)
          acc[mf][nf] = __builtin_amdgcn_mfma_f32_32x32x16_bf16(af[mf], bfr[nf], acc[mf][nf], 0, 0, 0);
    }
    __syncthreads();
  }
  #pragma unroll
  for (int mf = 0; mf < 2; mf++)
    #pragma unroll
    for (int nf = 0; nf < 2; nf++) {
      int l = n0 + wc * 64 + nf * 32 + l31;
      #pragma unroll
      for (int r = 0; r < 16; r++) {
        int d = m0 + wr * 64 + mf * 32 + (r & 3) + ((r >> 2) << 3) + (lh << 2);
        vpT[((size_t)z * 512 + d) * 2048 + l] = f2bf(acc[mf][nf][r]);
      }
    }
}

// ---------------- bf16 MFMA GEMM (fc only) ----------------
__global__ __launch_bounds__(256) void gemm_bf16_fc(const unsigned short* __restrict__ A,
    const unsigned short* __restrict__ Bt, float* __restrict__ Cout,
    int M, int N, int K) {
  __shared__ unsigned short As[64][72];
  __shared__ unsigned short Bs[128][72];
  int tid = threadIdx.x;
  int lane = tid & 63, wave = tid >> 6;
  int wr = wave >> 1, wc = wave & 1;
  int m0 = blockIdx.y * 64, n0 = blockIdx.x * 128;
  f32x4 acc[2][4];
  #pragma unroll
  for (int mi = 0; mi < 2; mi++)
    #pragma unroll
    for (int ni = 0; ni < 4; ni++) acc[mi][ni] = (f32x4){0.f, 0.f, 0.f, 0.f};
  int arow = tid >> 2, akc = (tid & 3) << 4;
  int brow = tid >> 1, bkc = (tid & 1) << 5;
  for (int k0 = 0; k0 < K; k0 += 64) {
    {
      const bfrag8* s = (const bfrag8*)(A + (size_t)(m0 + arow) * K + k0 + akc);
      *(bfrag8*)&As[arow][akc + 0] = s[0];
      *(bfrag8*)&As[arow][akc + 8] = s[1];
    }
    {
      const bfrag8* s = (const bfrag8*)(Bt + (size_t)(n0 + brow) * K + k0 + bkc);
      #pragma unroll
      for (int j = 0; j < 4; j++)
        *(bfrag8*)&Bs[brow][bkc + 8*j] = s[j];
    }
    __syncthreads();
    #pragma unroll
    for (int kh = 0; kh < 2; kh++) {
      int krd = (kh << 5) + ((lane >> 4) << 3);
      bfrag8 af[2], bfr[4];
      #pragma unroll
      for (int mi = 0; mi < 2; mi++)
        af[mi] = *(const bfrag8*)&As[wr*32 + mi*16 + (lane & 15)][krd];
      #pragma unroll
      for (int ni = 0; ni < 4; ni++)
        bfr[ni] = *(const bfrag8*)&Bs[wc*64 + ni*16 + (lane & 15)][krd];
      #pragma unroll
      for (int mi = 0; mi < 2; mi++)
        #pragma unroll
        for (int ni = 0; ni < 4; ni++)
          acc[mi][ni] = __builtin_amdgcn_mfma_f32_16x16x32_bf16(af[mi], bfr[ni], acc[mi][ni], 0, 0, 0);
    }
    __syncthreads();
  }
  #pragma unroll
  for (int mi = 0; mi < 2; mi++) {
    int rb = m0 + wr*32 + mi*16 + ((lane >> 4) << 2);
    #pragma unroll
    for (int ni = 0; ni < 4; ni++) {
      int col = n0 + wc*64 + ni*16 + (lane & 15);
      f32x4 v = acc[mi][ni];
      #pragma unroll
      for (int j = 0; j < 4; j++)
        Cout[(size_t)(rb + j)*512 + col] = v[j];
    }
  }
}

// ---------------- PV: probs[z][2048][2048] f32 x vpT[z][512][2048] -> mixed bf16 ----------------
__global__ __launch_bounds__(512) void pv_kernel(const float* __restrict__ probs,
    const unsigned short* __restrict__ vpT, unsigned short* __restrict__ mixed) {
  __shared__ unsigned short As[64][64];
  __shared__ unsigned short Bs[512][64];
  int tid = threadIdx.x;
  int lane = tid & 63, wv = tid >> 6;
  int l31 = lane & 31, lh = lane >> 5;
  int z = blockIdx.z, m0 = blockIdx.y * 64;
  const float* Ap = probs + (size_t)z * 2048 * 2048 + (size_t)m0 * 2048;
  const unsigned short* Bp = vpT + (size_t)z * 512 * 2048;
  f32x16 acc[2][2];
  #pragma unroll
  for (int mf = 0; mf < 2; mf++)
    #pragma unroll
    for (int nf = 0; nf < 2; nf++)
      #pragma unroll
      for (int r = 0; r < 16; r++) acc[mf][nf][r] = 0.f;
  int a_r = tid >> 3, a_c = tid & 7;
  for (int k0 = 0; k0 < 2048; k0 += 64) {
    {
      const float* s = Ap + (size_t)a_r * 2048 + k0 + a_c * 8;
      float4 x0 = *(const float4*)s;
      float4 x1 = *(const float4*)(s + 4);
      union { bfrag8 v; unsigned short u[8]; } p;
      p.u[0]=f2bf(x0.x); p.u[1]=f2bf(x0.y); p.u[2]=f2bf(x0.z); p.u[3]=f2bf(x0.w);
      p.u[4]=f2bf(x1.x); p.u[5]=f2bf(x1.y); p.u[6]=f2bf(x1.z); p.u[7]=f2bf(x1.w);
      *(bfrag8*)&As[a_r][((a_c + a_r) & 7) * 8] = p.v;
    }
    #pragma unroll
    for (int s = 0; s < 8; s++) {
      int n = (tid >> 3) + (s << 6);
      bfrag8 vb = *(const bfrag8*)(Bp + (size_t)n * 2048 + k0 + a_c * 8);
      *(bfrag8*)&Bs[n][((a_c + n) & 7) * 8] = vb;
    }
    __syncthreads();
    #pragma unroll
    for (int ks = 0; ks < 4; ks++) {
      int qd = ks * 2 + lh;
      bfrag8 af[2], bfr[2];
      #pragma unroll
      for (int mf = 0; mf < 2; mf++) {
        int r = mf * 32 + l31;
        af[mf] = *(const bfrag8*)&As[r][((qd + r) & 7) * 8];
      }
      #pragma unroll
      for (int nf = 0; nf < 2; nf++) {
        int n = wv * 64 + nf * 32 + l31;
        bfr[nf] = *(const bfrag8*)&Bs[n][((qd + n) & 7) * 8];
      }
      #pragma unroll
      for (int mf = 0; mf < 2; mf++)
        #pragma unroll
        for (int nf = 0; nf < 2; nf++)
          acc[mf][nf] = __builtin_amdgcn_mfma_f32_32x32x16_bf16(af[mf], bfr[nf], acc[mf][nf], 0, 0, 0);
    }
    __syncthreads();
  }
  int bb = z >> 3, h = z & 7;
  #pragma unroll
  for (int mf = 0; mf < 2; mf++)
    #pragma unroll
    for (int nf = 0; nf < 2; nf++) {
      int n = wv * 64 + nf * 32 + l31;
      #pragma unroll
      for (int r = 0; r < 16; r++) {
        int row = m0 + mf * 32 + (r & 3) + ((r >> 2) << 3) + (lh << 2);
        mixed[((size_t)bb * 2048 + row) * 4096 + h * 512 + n] = f2bf(acc[mf][nf][r]);
      }
    }
}

// ---------------- per-row top-k + softmax (one wave per row, in-place) ----------------
__global__ __launch_bounds__(256) void topk_softmax_k(float* __restrict__ probs,
    const float* __restrict__ qmaskf) {
  int lane = threadIdx.x & 63;
  int row = blockIdx.x * 4 + (threadIdx.x >> 6);
  int b = row >> 14, q = row & 2047;
  float* rp = probs + (size_t)row * 2048;
  unsigned key[32];
  #pragma unroll
  for (int j = 0; j < 8; j++) {
    int base = (lane << 2) + (j << 8);
    float4 v = *(const float4*)(rp + base);
    key[4*j+0] = mono(v.x);
    key[4*j+1] = mono(v.y);
    key[4*j+2] = mono(v.z);
    key[4*j+3] = mono(v.w);
  }
  unsigned drop = 0;
  bool qm = qmaskf[b * 2048 + q] > 0.5f;
  if (qm) {
    unsigned lo = 0u, hi = 0xFFFFu;
    while (lo < hi) {
      unsigned mid = lo + ((hi - lo + 1u) >> 1);
      unsigned t = mid << 16;
      int c = 0;
      #pragma unroll
      for (int e = 0; e < 32; e++) c += (key[e] >= t) ? 1 : 0;
      c = waveSum(c);
      if (c >= TOPK) lo = mid; else hi = mid - 1u;
    }
    unsigned P = lo;
    unsigned hiMax = (P << 16) | 0xFFFFu;
    int cgt_hi = 0;
    #pragma unroll
    for (int e = 0; e < 32; e++) cgt_hi += (key[e] > hiMax) ? 1 : 0;
    cgt_hi = waveSum(cgt_hi);
    int remaining = TOPK - cgt_hi;
    unsigned cur = 0xFFFFFFFFu;
    unsigned K64 = P << 16;
    for (;;) {
      unsigned mx = 0;
      #pragma unroll
      for (int e = 0; e < 32; e++) {
        unsigned kk = key[e];
        if ((kk >> 16) == P && kk < cur) mx = mx > kk ? mx : kk;
      }
      mx = waveMaxU(mx);
      int ce = 0;
      #pragma unroll
      for (int e = 0; e < 32; e++) ce += (key[e] == mx) ? 1 : 0;
      ce = waveSum(ce);
      if (remaining <= ce) { K64 = mx; break; }
      remaining -= ce;
      cur = mx;
    }
    int cgt = 0, ceq = 0;
    #pragma unroll
    for (int e = 0; e < 32; e++) { cgt += (key[e] > K64) ? 1 : 0; ceq += (key[e] == K64) ? 1 : 0; }
    cgt = waveSum(cgt);
    int ceqT = waveSum(ceq);
    int r = TOPK - cgt;
    #pragma unroll
    for (int e = 0; e < 32; e++) if (key[e] < K64) drop |= (1u << e);
    if (ceqT > r) {
      int taken = 0;
      for (int j = 0; j < 8; j++) {
        int cl = 0, eqm = 0;
        #pragma unroll
        for (int t = 0; t < 4; t++)
          if (key[4*j+t] == K64) { eqm |= (1 << t); cl++; }
        int incl = cl;
        for (int o = 1; o < 64; o <<= 1) {
          int tt = __shfl_up(incl, o);
          if (lane >= o) incl += tt;
        }
        int pref = incl - cl;
        int tot = __shfl(incl, 63);
        int rk = taken + pref;
        #pragma unroll
        for (int t = 0; t < 4; t++) {
          if ((eqm >> t) & 1) {
            if (rk >= r) drop |= (1u << (4*j+t));
            rk++;
          }
        }
        taken += tot;
      }
    }
  }
  unsigned kmax = 0;
  #pragma unroll
  for (int e = 0; e < 32; e++)
    if (!((drop >> e) & 1u)) kmax = kmax > key[e] ? kmax : key[e];
  kmax = waveMaxU(kmax);
  float mx = invmono(kmax);
  float ex[32]; float s = 0.f;
  #pragma unroll
  for (int e = 0; e < 32; e++) {
    float t = ((drop >> e) & 1u) ? 0.f : __expf(invmono(key[e]) - mx);
    ex[e] = t; s += t;
  }
  s = waveSumF(s);
  float inv = 1.0f / s;
  #pragma unroll
  for (int j = 0; j < 8; j++) {
    int base = (lane << 2) + (j << 8);
    float4 o;
    o.x = ex[4*j+0]*inv; o.y = ex[4*j+1]*inv; o.z = ex[4*j+2]*inv; o.w = ex[4*j+3]*inv;
    *(float4*)(rp + base) = o;
  }
}

extern "C" void kernel_launch(void* const* d_in, const int* in_sizes, int n_in,
                              void* d_out, int out_size, void* d_ws, size_t ws_size,
                              hipStream_t stream) {
  (void)in_sizes; (void)n_in; (void)out_size; (void)ws_size;
  const float* q     = (const float*)d_in[0];
  const float* k     = (const float*)d_in[1];
  const float* v     = (const float*)d_in[2];
  const int*   mask  = (const int*)d_in[3];
  const float* qmask = (const float*)d_in[4];
  const float* Wq    = (const float*)d_in[5];
  const float* Wk    = (const float*)d_in[6];
  const float* Wv    = (const float*)d_in[7];
  const float* Wfc   = (const float*)d_in[8];

  float* out   = (float*)d_out;                 // [2,2048,512]
  float* probs = out + 2097152;                 // [2,8,2048,2048] (logits then probs, in place)

  char* ws = (char*)d_ws;
  float*          qp    = (float*)(ws + 0);             // [B,H,Lq,64] (pre-scaled by 1/8)
  float*          kp    = (float*)(ws + 8388608);       // [B,H,Lk,64]
  unsigned short* vpT   = (unsigned short*)(ws + 16777216);  // [B,H,512,2048] bf16
  unsigned short* mixed = (unsigned short*)(ws + 50331648);  // [4096,4096] bf16
  float*          WqT   = (float*)(ws + 83886080);      // [512,512]
  float*          WkT   = (float*)(ws + 84934656);      // [512,512]
  unsigned short* WvT   = (unsigned short*)(ws + 85983232);  // [4096,512] bf16
  unsigned short* WfcT  = (unsigned short*)(ws + 90177536);  // [512,4096] bf16

  transpose_k<0><<<dim3(16, 16),  256, 0, stream>>>(Wq,  WqT,  512, 512);
  transpose_k<0><<<dim3(16, 16),  256, 0, stream>>>(Wk,  WkT,  512, 512);
  transpose_k<1><<<dim3(128, 16), 256, 0, stream>>>(Wv,  WvT,  512, 4096);
  transpose_k<1><<<dim3(16, 128), 256, 0, stream>>>(Wfc, WfcT, 4096, 512);

  // fp32 projections, q and k merged (top-k path must be fp32-exact)
  proj_f32_kernel<<<dim3(4, 32, 2), 256, 0, stream>>>(q, k, WqT, WkT, qp, kp);

  // v_proj per (b,h): A=WvT slice (bf16, K-contiguous), B=v[b] (K-contiguous)
  vproj_kernel<<<dim3(16, 4, 16), 256, 0, stream>>>(v, WvT, vpT);

  // fp32 logits with fused post-softmax mask -> probs region
  logits_mask_kernel<<<dim3(16, 16, 16), 256, 0, stream>>>(qp, kp, mask, probs);

  // exact top-64 + softmax, in place
  topk_softmax_k<<<dim3(8192), 256, 0, stream>>>(probs, qmask);

  // PV: probs (f32->bf16 at staging) x vpT -> mixed bf16
  pv_kernel<<<dim3(1, 32, 16), 512, 0, stream>>>(probs, vpT, mixed);

  // fc: mixed x WfcT -> output f32
  gemm_bf16_fc<<<dim3(4, 64), 256, 0, stream>>>(mixed, WfcT, out, 4096, 512, 4096);
}